// Round 1
// baseline (346.917 us; speedup 1.0000x reference)
//
#include <hip/hip_runtime.h>

#define DEVINL __device__ __forceinline__

namespace {
constexpr int NB = 2;
constexpr int NN = 4096;
constexpr int KK = 32;
constexpr int NP = NN * KK;      // 131072 (points*K per batch)
constexpr float R2 = 0.01f;      // RADIUS^2
constexpr float GEPS = 1e-5f;
}

// angle(v1,v2) = atan2(|v1 x v2|, v1.v2) with degenerate guard (reference-exact)
DEVINL float angle3(float ax, float ay, float az, float bx, float by, float bz) {
    float crx = ay * bz - az * by;
    float cry = az * bx - ax * bz;
    float crz = ax * by - ay * bx;
    float sq = crx * crx + cry * cry + crz * crz;
    float yv = sq > 0.f ? sqrtf(sq) : 0.f;
    float xv = ax * bx + ay * by + az * bz;
    if (yv == 0.f && xv == 0.f) return 0.f;
    return atan2f(yv, xv);
}

// block = 256 threads (4 waves). Each thread holds NV partials; sum across block,
// then atomicAdd to gout[0..NV)
template <int NV>
DEVINL void blockReduceAdd(float* vals, float* __restrict__ gout) {
    #pragma unroll
    for (int m = 1; m < 64; m <<= 1) {
        #pragma unroll
        for (int q = 0; q < NV; ++q) vals[q] += __shfl_xor(vals[q], m, 64);
    }
    __shared__ float red[4][NV];
    int lane = threadIdx.x & 63, w = threadIdx.x >> 6;
    if (lane == 0) {
        #pragma unroll
        for (int q = 0; q < NV; ++q) red[w][q] = vals[q];
    }
    __syncthreads();
    if ((int)threadIdx.x < NV) {
        float v = red[0][threadIdx.x] + red[1][threadIdx.x] +
                  red[2][threadIdx.x] + red[3][threadIdx.x];
        atomicAdd(&gout[threadIdx.x], v);
    }
}

// Transpose weights so the conv inner loops read W contiguously with uniform
// (scalar-load-friendly) addresses: wNt[c*Cout + o] = wN[o*Cin + c]
__global__ void k_prep(const float* __restrict__ w0, const float* __restrict__ w1,
                       const float* __restrict__ w2, float* __restrict__ w0t,
                       float* __restrict__ w1t, float* __restrict__ w2t) {
    int t = threadIdx.x;
    for (int x = t; x < 64 * 13; x += 256) { int o = x / 13, c = x % 13; w0t[c * 64 + o] = w0[x]; }
    for (int x = t; x < 64 * 64; x += 256) { int o = x / 64, c = x % 64; w1t[c * 64 + o] = w1[x]; }
    for (int x = t; x < 128 * 64; x += 256) { int o = x / 64, c = x % 64; w2t[c * 128 + o] = w2[x]; }
}

// Ball query: one wave per (b,i); first KK ascending indices with d2<=R2, pad with first.
__global__ __launch_bounds__(256) void k_ball(const float* __restrict__ xyz,
                                              int* __restrict__ idx) {
    int wid = blockIdx.x * 4 + (threadIdx.x >> 6);
    int lane = threadIdx.x & 63;
    int b = wid >> 12;
    int i = wid & (NN - 1);
    const float* xb = xyz + b * NN * 3;
    float cx = xb[i * 3 + 0], cy = xb[i * 3 + 1], cz = xb[i * 3 + 2];
    int* out = idx + wid * KK;
    int cnt = 0;
    int firstj = 0;
    for (int base = 0; base < NN; base += 64) {
        int j = base + lane;
        float dx = xb[j * 3 + 0] - cx;
        float dy = xb[j * 3 + 1] - cy;
        float dz = xb[j * 3 + 2] - cz;
        // no-fma, left-to-right sum: match XLA's d2 at the radius boundary
        float d2 = __fadd_rn(__fadd_rn(__fmul_rn(dx, dx), __fmul_rn(dy, dy)), __fmul_rn(dz, dz));
        bool valid = d2 <= R2;
        unsigned long long m = __ballot(valid);
        if (cnt == 0 && m != 0ull) firstj = base + (int)__builtin_ctzll(m);
        int pos = (int)__popcll(m & ((1ull << lane) - 1ull));
        if (valid && (cnt + pos) < KK) out[cnt + pos] = j;
        cnt += (int)__popcll(m);
        if (cnt >= KK) break;
    }
    if (cnt < KK) {
        int kpad = cnt + lane;
        if (kpad < KK) out[kpad] = firstj;
    }
}

// Per (b,i,k): compute the 13 fused channels, write them (c-major), and
// accumulate GN stats of conv0's output (computed in registers, discarded).
__global__ __launch_bounds__(256) void k_feat(
    const float* __restrict__ xyz, const float* __restrict__ feat,
    const int* __restrict__ idx, const float* __restrict__ w0t,
    const float* __restrict__ wap, const float* __restrict__ wbp,
    const float* __restrict__ wcp, float* __restrict__ f13,
    float* __restrict__ stats0) {
    int t = blockIdx.x * 256 + threadIdx.x;
    int b = t / NP, r = t % NP;
    int i = r >> 5;
    int j = idx[t];
    const float* xb = xyz + b * NN * 3;
    const float* fb = feat + b * NN * 3;
    float cx = xb[i * 3], cy = xb[i * 3 + 1], cz = xb[i * 3 + 2];
    float nx = fb[i * 3], ny = fb[i * 3 + 1], nz = fb[i * 3 + 2];
    float gx = xb[j * 3], gy = xb[j * 3 + 1], gz = xb[j * 3 + 2];
    float mx = fb[j * 3], my = fb[j * 3 + 1], mz = fb[j * 3 + 2];
    float dx = gx - cx, dy = gy - cy, dz = gz - cz;
    float d2 = dx * dx + dy * dy + dz * dz;
    float dist = d2 > 0.f ? sqrtf(d2) : 0.f;
    float a1 = angle3(nx, ny, nz, dx, dy, dz);
    float a2 = angle3(mx, my, mz, dx, dy, dz);
    float a3 = angle3(nx, ny, nz, mx, my, mz);
    float WA = wap[0], WB = wbp[0], WC = wcp[0];
    float f[13] = {WA * cx, WA * cy, WA * cz, WA * gx, WA * gy, WA * gz,
                   WB * dx, WB * dy, WB * dz, WB * dist, WC * a1, WC * a2, WC * a3};
    float* fo = f13 + (size_t)b * 13 * NP + r;
    #pragma unroll
    for (int c = 0; c < 13; ++c) fo[(size_t)c * NP] = f[c];
    // conv0 in registers, for stats only
    float acc[64];
    #pragma unroll
    for (int o = 0; o < 64; ++o) acc[o] = 0.f;
    #pragma unroll
    for (int c = 0; c < 13; ++c) {
        float v = f[c];
        const float* wr = w0t + c * 64;
        #pragma unroll
        for (int o = 0; o < 64; ++o) acc[o] = fmaf(wr[o], v, acc[o]);
    }
    float vals[16];
    #pragma unroll
    for (int g = 0; g < 8; ++g) {
        float sv = 0.f, sq = 0.f;
        #pragma unroll
        for (int c2 = 0; c2 < 8; ++c2) { float v = acc[g * 8 + c2]; sv += v; sq = fmaf(v, v, sq); }
        vals[g * 2] = sv; vals[g * 2 + 1] = sq;
    }
    blockReduceAdd<16>(vals, stats0 + b * 16);
}

// conv0 -> GN0 -> relu -> conv1; write raw y1 + accumulate stats1.
__global__ __launch_bounds__(256) void k_conv01(
    const float* __restrict__ f13, const float* __restrict__ stats0,
    const float* __restrict__ g0, const float* __restrict__ b0,
    const float* __restrict__ w0t, const float* __restrict__ w1t,
    float* __restrict__ y1, float* __restrict__ stats1) {
    __shared__ float A[64], Bc[64];
    int t = blockIdx.x * 256 + threadIdx.x;
    int b = t / NP, r = t % NP;
    if (threadIdx.x < 64) {
        int c = threadIdx.x, g = c >> 3;
        const float inv = 1.f / 1048576.f;  // (64/8)*K*N
        float s = stats0[b * 16 + g * 2], q = stats0[b * 16 + g * 2 + 1];
        float mean = s * inv;
        float var = q * inv - mean * mean;
        float rstd = rsqrtf(var + GEPS);
        float a = rstd * g0[c];
        A[c] = a; Bc[c] = fmaf(-mean, a, b0[c]);
    }
    __syncthreads();
    float h[64];
    #pragma unroll
    for (int o = 0; o < 64; ++o) h[o] = 0.f;
    const float* fi = f13 + (size_t)b * 13 * NP + r;
    #pragma unroll
    for (int c = 0; c < 13; ++c) {
        float v = fi[(size_t)c * NP];
        const float* wr = w0t + c * 64;
        #pragma unroll
        for (int o = 0; o < 64; ++o) h[o] = fmaf(wr[o], v, h[o]);
    }
    #pragma unroll
    for (int o = 0; o < 64; ++o) {
        float v = fmaf(A[o], h[o], Bc[o]);
        h[o] = v > 0.f ? v : 0.f;
    }
    float acc[64];
    #pragma unroll
    for (int o = 0; o < 64; ++o) acc[o] = 0.f;
    #pragma unroll
    for (int m = 0; m < 64; ++m) {
        float v = h[m];
        const float* wr = w1t + m * 64;
        #pragma unroll
        for (int o = 0; o < 64; ++o) acc[o] = fmaf(wr[o], v, acc[o]);
    }
    float vals[16];
    #pragma unroll
    for (int g = 0; g < 8; ++g) {
        float sv = 0.f, sq = 0.f;
        #pragma unroll
        for (int c2 = 0; c2 < 8; ++c2) { float v = acc[g * 8 + c2]; sv += v; sq = fmaf(v, v, sq); }
        vals[g * 2] = sv; vals[g * 2 + 1] = sq;
    }
    float* yo = y1 + (size_t)b * 64 * NP + r;
    #pragma unroll
    for (int o = 0; o < 64; ++o) yo[(size_t)o * NP] = acc[o];
    blockReduceAdd<16>(vals, stats1 + b * 16);
}

// GN1+relu on y1, conv2 (this block's 64-channel half), stats2, and the
// K-extreme (max if gamma2>=0 else min — max/relu commute with the GN affine).
__global__ __launch_bounds__(256) void k_conv2(
    const float* __restrict__ y1, const float* __restrict__ stats1,
    const float* __restrict__ g1, const float* __restrict__ b1,
    const float* __restrict__ g2, const float* __restrict__ w2t,
    float* __restrict__ ext, float* __restrict__ stats2) {
    __shared__ float A[64], Bc[64];
    int half = blockIdx.y;
    int t = blockIdx.x * 256 + threadIdx.x;
    int b = t / NP, r = t % NP;
    if (threadIdx.x < 64) {
        int c = threadIdx.x, g = c >> 3;
        const float inv = 1.f / 1048576.f;
        float s = stats1[b * 16 + g * 2], q = stats1[b * 16 + g * 2 + 1];
        float mean = s * inv;
        float var = q * inv - mean * mean;
        float rstd = rsqrtf(var + GEPS);
        float a = rstd * g1[c];
        A[c] = a; Bc[c] = fmaf(-mean, a, b1[c]);
    }
    __syncthreads();
    float acc[64];
    #pragma unroll
    for (int o = 0; o < 64; ++o) acc[o] = 0.f;
    const float* yi = y1 + (size_t)b * 64 * NP + r;
    #pragma unroll 4
    for (int c = 0; c < 64; ++c) {
        float v = yi[(size_t)c * NP];
        v = fmaf(A[c], v, Bc[c]);
        v = v > 0.f ? v : 0.f;
        const float* wr = w2t + c * 128 + half * 64;
        #pragma unroll
        for (int o = 0; o < 64; ++o) acc[o] = fmaf(wr[o], v, acc[o]);
    }
    // stats2: this half's channels are 4 groups of 16
    float vals[8];
    #pragma unroll
    for (int g = 0; g < 4; ++g) {
        float sv = 0.f, sq = 0.f;
        #pragma unroll
        for (int c2 = 0; c2 < 16; ++c2) { float v = acc[g * 16 + c2]; sv += v; sq = fmaf(v, v, sq); }
        vals[g * 2] = sv; vals[g * 2 + 1] = sq;
    }
    blockReduceAdd<8>(vals, stats2 + b * 16 + half * 8);
    // K-reduction: K=32 == half-wave; lanes 0..31 share i, lanes 32..63 share i+1
    #pragma unroll
    for (int o = 0; o < 64; ++o) {
        bool takeMax = g2[half * 64 + o] >= 0.f;
        float e = acc[o];
        #pragma unroll
        for (int m = 1; m < 32; m <<= 1) {
            float e2 = __shfl_xor(e, m, 64);
            e = takeMax ? fmaxf(e, e2) : fminf(e, e2);
        }
        acc[o] = e;
    }
    int lane = threadIdx.x & 63;
    if ((lane & 31) == 0) {
        int i = r >> 5;
        float* eo = ext + ((size_t)b * 128 + half * 64) * NN + i;
        #pragma unroll
        for (int o = 0; o < 64; ++o) eo[(size_t)o * NN] = acc[o];
    }
}

// Apply GN2 affine to the extremes; write out = relu(val) and x = val.
__global__ __launch_bounds__(256) void k_final(
    const float* __restrict__ ext, const float* __restrict__ stats2,
    const float* __restrict__ g2, const float* __restrict__ b2,
    float* __restrict__ outp) {
    __shared__ float A[128], Bc[128];
    int t = blockIdx.x * 256 + threadIdx.x;
    int b = t / (128 * NN);
    int rem = t - b * 128 * NN;
    int c = rem >> 12;  // /NN
    if (threadIdx.x < 128) {
        int cc = threadIdx.x, g = cc >> 4;
        const float inv = 1.f / 2097152.f;  // (128/8)*K*N
        float s = stats2[b * 16 + g * 2], q = stats2[b * 16 + g * 2 + 1];
        float mean = s * inv;
        float var = q * inv - mean * mean;
        float rstd = rsqrtf(var + GEPS);
        float a = rstd * g2[cc];
        A[cc] = a; Bc[cc] = fmaf(-mean, a, b2[cc]);
    }
    __syncthreads();
    float v = ext[t];
    float val = fmaf(A[c], v, Bc[c]);
    outp[t] = fmaxf(val, 0.f);
    outp[NB * 128 * NN + t] = val;
}

extern "C" void kernel_launch(void* const* d_in, const int* in_sizes, int n_in,
                              void* d_out, int out_size, void* d_ws, size_t ws_size,
                              hipStream_t stream) {
    const float* feat = (const float*)d_in[0];
    const float* xyz  = (const float*)d_in[1];
    const float* w0 = (const float*)d_in[2];
    const float* g0 = (const float*)d_in[3];
    const float* b0 = (const float*)d_in[4];
    const float* w1 = (const float*)d_in[5];
    const float* g1 = (const float*)d_in[6];
    const float* b1 = (const float*)d_in[7];
    const float* w2 = (const float*)d_in[8];
    const float* g2 = (const float*)d_in[9];
    const float* b2 = (const float*)d_in[10];
    const float* wa = (const float*)d_in[11];
    const float* wb = (const float*)d_in[12];
    const float* wc = (const float*)d_in[13];

    char* ws = (char*)d_ws;
    float* stats = (float*)ws;               // 96 floats (3 layers x B x G x {s,ss})
    float* w0t = (float*)(ws + 4096);        // 832 floats
    float* w1t = (float*)(ws + 8192);        // 4096 floats
    float* w2t = (float*)(ws + 24576);       // 8192 floats
    int*   idx = (int*)(ws + 65536);         // B*N*K ints (1 MiB)
    float* f13 = (float*)(ws + (2ull << 20));   // 13.6 MB
    float* y1  = (float*)(ws + (16ull << 20));  // 64 MiB
    float* ext = (float*)(ws + (80ull << 20));  // 4 MiB   (total ~84 MiB)

    hipMemsetAsync(stats, 0, 512, stream);
    hipLaunchKernelGGL(k_prep, dim3(1), dim3(256), 0, stream, w0, w1, w2, w0t, w1t, w2t);
    hipLaunchKernelGGL(k_ball, dim3((NB * NN) / 4), dim3(256), 0, stream, xyz, idx);
    hipLaunchKernelGGL(k_feat, dim3((NB * NP) / 256), dim3(256), 0, stream,
                       xyz, feat, idx, w0t, wa, wb, wc, f13, stats);
    hipLaunchKernelGGL(k_conv01, dim3((NB * NP) / 256), dim3(256), 0, stream,
                       f13, stats, g0, b0, w0t, w1t, y1, stats + 32);
    hipLaunchKernelGGL(k_conv2, dim3((NB * NP) / 256, 2), dim3(256), 0, stream,
                       y1, stats + 32, g1, b1, g2, w2t, ext, stats + 64);
    hipLaunchKernelGGL(k_final, dim3((NB * 128 * NN) / 256), dim3(256), 0, stream,
                       ext, stats + 64, g2, b2, (float*)d_out);
}